// Round 3
// baseline (331.892 us; speedup 1.0000x reference)
//
#include <hip/hip_runtime.h>

#define HH 256
#define WW 256
#define CC 64
#define FF 128
#define NN 8
#define OUTC 384           // 3*C sep + C lap + F learned
#define HW (HH * WW)

typedef __attribute__((ext_vector_type(8))) short bf16x8;
typedef __attribute__((ext_vector_type(4))) float f32x4;

__device__ __forceinline__ int clampi(int v, int lo, int hi) {
    return v < lo ? lo : (v > hi ? hi : v);
}

// round-to-nearest-even fp32 -> bf16
static __device__ __forceinline__ unsigned short f2bf(float x) {
    unsigned u = __builtin_bit_cast(unsigned, x);
    u += 0x7FFFu + ((u >> 16) & 1u);
    return (unsigned short)(u >> 16);
}
static __device__ __forceinline__ unsigned packbf(float a, float b) {
    return (unsigned)f2bf(a) | ((unsigned)f2bf(b) << 16);
}
static __device__ __forceinline__ float bfl(unsigned v) {
    return __builtin_bit_cast(float, v << 16);
}
static __device__ __forceinline__ float bfh(unsigned v) {
    return __builtin_bit_cast(float, v & 0xffff0000u);
}

// ---------------------------------------------------------------------------
// Kernel 0: W[f][c][3][3] fp32 -> ws bf16 [tap][f][c]   (9*128*64 elems)
// ---------------------------------------------------------------------------
__global__ __launch_bounds__(256) void wT_kernel(const float* __restrict__ Wl,
                                                 unsigned* __restrict__ wsW) {
    int e = blockIdx.x * 256 + threadIdx.x;     // over 9*128*32 = 36864 pairs
    if (e >= 9 * 128 * 32) return;
    int t = e >> 12;
    int rem = e & 4095;
    int f = rem >> 5;
    int c2 = rem & 31;
    float a = Wl[(size_t)f * 576 + (size_t)(2 * c2) * 9 + t];
    float b = Wl[(size_t)f * 576 + (size_t)(2 * c2 + 1) * 9 + t];
    wsW[t * 4096 + f * 32 + c2] = packbf(a, b);
}

// ---------------------------------------------------------------------------
// Fused kernel: learned dense 3x3 conv via bf16 MFMA (tap-decomposed implicit
// GEMM) + depthwise fixed filters computed from the same staged x tile.
// block = 512 thr (8 waves). out tile = 16x16 px; learned: 128 f; dw: 64c x4.
// LDS: x-tile [324 pix][64 ch] bf16 (XOR-swizzled), W per-tap [128 f][64 c] x2
// dw work split into 8 chunks (2 rows each), one per tap iteration, so its
// global stores drain under the MFMA compute.
// ---------------------------------------------------------------------------
__global__ __launch_bounds__(512, 4) void fused_kernel(const float* __restrict__ x,
                                                       const unsigned short* __restrict__ wsW,
                                                       const float* __restrict__ bl,
                                                       float* __restrict__ out) {
    __shared__ __align__(16) unsigned char lds_x[324 * 128];      // 41472 B
    __shared__ __align__(16) unsigned char lds_w[2][128 * 128];   // 32768 B

    int blk = blockIdx.x;                 // n*256 + ty*16 + tx
    int tile = blk & 255;
    int n = blk >> 8;
    int ty0 = (tile >> 4) * 16;
    int tx0 = (tile & 15) * 16;

    int tid = threadIdx.x;
    int lane = tid & 63;
    int w = tid >> 6;
    int wf = w >> 2;                      // f-half (0..1)
    int wp = w & 3;                       // px-quarter (0..3): rows wp*4..wp*4+3
    int lr = lane & 15;                   // frag row/col index
    int lk = lane >> 4;                   // frag K group (0..3)

    // ---- stage x tile (once): fp32 global -> bf16 LDS [pix][ch], swizzled
    const float* xb = x + (size_t)n * CC * HW;
    for (int e = tid; e < 324 * 32; e += 512) {
        int c2 = e / 324;
        int pix = e - c2 * 324;
        int hy = pix / 18;
        int hx = pix - hy * 18;
        int gy = clampi(ty0 - 1 + hy, 0, HH - 1);
        int gx = clampi(tx0 - 1 + hx, 0, WW - 1);
        size_t gi = (size_t)(2 * c2) * HW + (size_t)gy * WW + gx;
        unsigned v = packbf(xb[gi], xb[gi + HW]);
        int addr = pix * 128 + ((c2 * 4) ^ ((pix & 7) << 4));
        *reinterpret_cast<unsigned*>(lds_x + addr) = v;
    }
    // ---- stage W tap 0 into buffer 0
#pragma unroll
    for (int i = 0; i < 2; ++i) {
        int e = tid + i * 512;
        int f = e >> 3, cg = e & 7;
        uint4 v = *reinterpret_cast<const uint4*>(wsW + (f * 64 + cg * 8));
        int addr = (f * 128 + cg * 16) ^ ((f & 7) << 4);
        *reinterpret_cast<uint4*>(lds_w[0] + addr) = v;
    }
    __syncthreads();

    f32x4 acc[4][4] = {};                 // [mt (f tile)][pb (px frag)]

    for (int t = 0; t < 9; ++t) {
        int dy = t / 3, dx = t - 3 * (t / 3);

        // T14: issue next-tap W loads early (consumed after compute)
        uint4 wreg[2];
        if (t < 8) {
#pragma unroll
            for (int i = 0; i < 2; ++i) {
                int e = tid + i * 512;
                int f = e >> 3, cg = e & 7;
                wreg[i] = *reinterpret_cast<const uint4*>(wsW + ((t + 1) * 8192 + f * 64 + cg * 8));
            }
        }

        const unsigned char* wbuf = lds_w[t & 1];
#pragma unroll
        for (int kk = 0; kk < 2; ++kk) {
            int off = kk * 64 + lk * 16;
            bf16x8 a[4], b[4];
#pragma unroll
            for (int mt = 0; mt < 4; ++mt) {
                int f = wf * 64 + mt * 16 + lr;
                int addr = f * 128 + (off ^ ((f & 7) << 4));
                a[mt] = *reinterpret_cast<const bf16x8*>(wbuf + addr);
            }
#pragma unroll
            for (int pb = 0; pb < 4; ++pb) {
                int pix = (wp * 4 + pb + dy) * 18 + (lr + dx);
                int addr = pix * 128 + (off ^ ((pix & 7) << 4));
                b[pb] = *reinterpret_cast<const bf16x8*>(lds_x + addr);
            }
#pragma unroll
            for (int mt = 0; mt < 4; ++mt)
#pragma unroll
                for (int pb = 0; pb < 4; ++pb)
                    acc[mt][pb] = __builtin_amdgcn_mfma_f32_16x16x32_bf16(
                        a[mt], b[pb], acc[mt][pb], 0, 0, 0);
        }

        // write next-tap W slab into the other buffer
        if (t < 8) {
#pragma unroll
            for (int i = 0; i < 2; ++i) {
                int e = tid + i * 512;
                int f = e >> 3, cg = e & 7;
                int addr = (f * 128 + cg * 16) ^ ((f & 7) << 4);
                *reinterpret_cast<uint4*>(lds_w[(t + 1) & 1] + addr) = wreg[i];
            }

            // ---- dw chunk t: rows 2t..2t+1, all 64 channels, 4 fixed filters
            int c2 = tid >> 4;            // channel pair 0..31
            int u = tid & 15;
            int r = 2 * t + (u >> 3);     // output row in tile
            int cxl = (u & 7) * 2;        // output col (2 px per thread)
            unsigned nb[3][4];
#pragma unroll
            for (int rr = 0; rr < 3; ++rr)
#pragma unroll
                for (int cc = 0; cc < 4; ++cc) {
                    int pix = (r + rr) * 18 + (cxl + cc);
                    nb[rr][cc] = *reinterpret_cast<const unsigned*>(
                        lds_x + pix * 128 + ((c2 * 4) ^ ((pix & 7) << 4)));
                }
            size_t nbase = (size_t)n * OUTC * HW + (size_t)(ty0 + r) * WW + (tx0 + cxl);
#pragma unroll
            for (int ch = 0; ch < 2; ++ch) {
                float tw[4], mw[4], bw[4];
#pragma unroll
                for (int cc = 0; cc < 4; ++cc) {
                    tw[cc] = ch ? bfh(nb[0][cc]) : bfl(nb[0][cc]);
                    mw[cc] = ch ? bfh(nb[1][cc]) : bfl(nb[1][cc]);
                    bw[cc] = ch ? bfh(nb[2][cc]) : bfl(nb[2][cc]);
                }
                float2 o0, o1, o2, o3;
#pragma unroll
                for (int j = 0; j < 2; ++j) {
                    float s0 = mw[j + 1];
                    float s1 = (tw[j] + 2.f * tw[j + 1] + tw[j + 2])
                             - (bw[j] + 2.f * bw[j + 1] + bw[j + 2]);
                    float s2 = (tw[j] - tw[j + 2]) + 2.f * (mw[j] - mw[j + 2])
                             + (bw[j] - bw[j + 2]);
                    float s3 = 4.f * mw[j + 1] - tw[j + 1] - bw[j + 1] - mw[j] - mw[j + 2];
                    (&o0.x)[j] = s0; (&o1.x)[j] = s1; (&o2.x)[j] = s2; (&o3.x)[j] = s3;
                }
                int c = c2 * 2 + ch;
                *reinterpret_cast<float2*>(out + nbase + (size_t)(c * 3 + 0) * HW) = o0;
                *reinterpret_cast<float2*>(out + nbase + (size_t)(c * 3 + 1) * HW) = o1;
                *reinterpret_cast<float2*>(out + nbase + (size_t)(c * 3 + 2) * HW) = o2;
                *reinterpret_cast<float2*>(out + nbase + (size_t)(192 + c) * HW) = o3;
            }
        }
        __syncthreads();
    }

    // ---- epilogue: bias + store. f = wf*64 + mt*16 + lk*4 + i ; px col = lr
#pragma unroll
    for (int mt = 0; mt < 4; ++mt) {
#pragma unroll
        for (int i = 0; i < 4; ++i) {
            int f = wf * 64 + mt * 16 + lk * 4 + i;
            float bv = bl[f];
            size_t ob = ((size_t)(n * OUTC) + 256 + f) * HW;
#pragma unroll
            for (int pb = 0; pb < 4; ++pb) {
                int r = wp * 4 + pb;
                out[ob + (size_t)(ty0 + r) * WW + (tx0 + lr)] = acc[mt][pb][i] + bv;
            }
        }
    }
}

extern "C" void kernel_launch(void* const* d_in, const int* in_sizes, int n_in,
                              void* d_out, int out_size, void* d_ws, size_t ws_size,
                              hipStream_t stream) {
    const float* x  = (const float*)d_in[0];
    const float* Wl = (const float*)d_in[1];
    const float* bl = (const float*)d_in[2];
    float* out = (float*)d_out;

    wT_kernel<<<144, 256, 0, stream>>>(Wl, (unsigned*)d_ws);
    fused_kernel<<<NN * 256, 512, 0, stream>>>(x, (const unsigned short*)d_ws, bl, out);
}

// Round 4
// 329.942 us; speedup vs baseline: 1.0059x; 1.0059x over previous
//
#include <hip/hip_runtime.h>

#define HH 256
#define WW 256
#define CC 64
#define FF 128
#define NN 8
#define OUTC 384           // 3*C sep + C lap + F learned
#define HW (HH * WW)

typedef __attribute__((ext_vector_type(8))) short bf16x8;
typedef __attribute__((ext_vector_type(4))) float f32x4;

__device__ __forceinline__ int clampi(int v, int lo, int hi) {
    return v < lo ? lo : (v > hi ? hi : v);
}

// round-to-nearest-even fp32 -> bf16
static __device__ __forceinline__ unsigned short f2bf(float x) {
    unsigned u = __builtin_bit_cast(unsigned, x);
    u += 0x7FFFu + ((u >> 16) & 1u);
    return (unsigned short)(u >> 16);
}
static __device__ __forceinline__ unsigned packbf(float a, float b) {
    return (unsigned)f2bf(a) | ((unsigned)f2bf(b) << 16);
}
static __device__ __forceinline__ float bfl(unsigned v) {
    return __builtin_bit_cast(float, v << 16);
}
static __device__ __forceinline__ float bfh(unsigned v) {
    return __builtin_bit_cast(float, v & 0xffff0000u);
}

// ---------------------------------------------------------------------------
// Kernel 0: W[f][c][3][3] fp32 -> ws bf16 [tap][f][c]   (9*128*64 elems)
// ---------------------------------------------------------------------------
__global__ __launch_bounds__(256) void wT_kernel(const float* __restrict__ Wl,
                                                 unsigned* __restrict__ wsW) {
    int e = blockIdx.x * 256 + threadIdx.x;     // over 9*128*32 = 36864 pairs
    if (e >= 9 * 128 * 32) return;
    int t = e >> 12;
    int rem = e & 4095;
    int f = rem >> 5;
    int c2 = rem & 31;
    float a = Wl[(size_t)f * 576 + (size_t)(2 * c2) * 9 + t];
    float b = Wl[(size_t)f * 576 + (size_t)(2 * c2 + 1) * 9 + t];
    wsW[t * 4096 + f * 32 + c2] = packbf(a, b);
}

// ---------------------------------------------------------------------------
// Fused kernel, 64x4 px tile x (128 learned f + 64c x 4 fixed filters).
// 512 thr / 8 waves. wave = wf (f-half) x wp (tile row); per wave 64f x 64px.
// LDS: x-tile only: [396 pix][64 ch] bf16, XOR-swizzled (50688 B).
// W (a-frags) read per-tap straight from L2 (147 KB resident, no lds_w,
// -> zero barriers in the 9-tap loop). dw: 1 channel per wave per tap,
// lane = x, scalar stores in 256B segments. Learned epilogue: 4x4 frag
// transpose through LDS (reuses lds_x), float4 stores in 256B segments.
// ---------------------------------------------------------------------------
__global__ __launch_bounds__(512, 2) void fused_kernel(const float* __restrict__ x,
                                                       const unsigned short* __restrict__ wsW,
                                                       const float* __restrict__ bl,
                                                       float* __restrict__ out) {
    __shared__ __align__(16) unsigned char lds_x[396 * 128];      // 50688 B

    int blk = blockIdx.x;                 // n*256 + ty*4 + tx
    int tile = blk & 255;
    int n = blk >> 8;
    int ty0 = (tile >> 2) * 4;            // 64 y-tiles of 4 rows
    int tx0 = (tile & 3) * 64;            // 4 x-tiles of 64 cols

    int tid = threadIdx.x;
    int lane = tid & 63;
    int w = tid >> 6;
    int wf = w >> 2;                      // f-half (0..1)
    int wp = w & 3;                       // tile row (0..3)
    int lr = lane & 15;
    int lk = lane >> 4;

    // ---- stage x tile: fp32 global -> bf16 LDS [pix][ch], swizzled. once.
    const float* xb = x + (size_t)n * CC * HW;
    for (int e = tid; e < 396 * 32; e += 512) {
        int cp = e / 396;
        int pix = e - cp * 396;
        int hy = pix / 66;
        int hx = pix - hy * 66;
        int gy = clampi(ty0 - 1 + hy, 0, HH - 1);
        int gx = clampi(tx0 - 1 + hx, 0, WW - 1);
        size_t gi = (size_t)(2 * cp) * HW + (size_t)gy * WW + gx;
        unsigned v = packbf(xb[gi], xb[gi + HW]);
        *reinterpret_cast<unsigned*>(lds_x + pix * 128 + ((cp * 4) ^ ((pix & 7) << 4))) = v;
    }
    __syncthreads();

    f32x4 acc[4][4] = {};                 // [mt (f tile)][j (16-px group)]

#pragma unroll
    for (int t = 0; t < 9; ++t) {
        int dy = t / 3, dx = t - 3 * (t / 3);

        // a-frags straight from L2-resident wsW[t][f][c]
        bf16x8 a[4][2];
#pragma unroll
        for (int mt = 0; mt < 4; ++mt)
#pragma unroll
            for (int kk = 0; kk < 2; ++kk) {
                int f = wf * 64 + mt * 16 + lr;
                a[mt][kk] = *reinterpret_cast<const bf16x8*>(
                    wsW + (size_t)t * 8192 + f * 64 + kk * 32 + lk * 8);
            }

#pragma unroll
        for (int kk = 0; kk < 2; ++kk) {
            int off = kk * 64 + lk * 16;
            bf16x8 b[4];
#pragma unroll
            for (int j = 0; j < 4; ++j) {
                int pix = (wp + dy) * 66 + j * 16 + lr + dx;
                b[j] = *reinterpret_cast<const bf16x8*>(
                    lds_x + pix * 128 + (off ^ ((pix & 7) << 4)));
            }
#pragma unroll
            for (int mt = 0; mt < 4; ++mt)
#pragma unroll
                for (int j = 0; j < 4; ++j)
                    acc[mt][j] = __builtin_amdgcn_mfma_f32_16x16x32_bf16(
                        a[mt][kk], b[j], acc[mt][j], 0, 0, 0);
        }

        // ---- dw chunk t: channel c = 8t + w, all 4 rows x 64 px, 4 filters
        if (t < 8) {
            int c = 8 * t + w;
            int cp2 = c >> 1, par = c & 1;
            float v[6][3];
#pragma unroll
            for (int hy = 0; hy < 6; ++hy)
#pragma unroll
                for (int cc = 0; cc < 3; ++cc) {
                    int pix = hy * 66 + lane + cc;
                    unsigned u = *reinterpret_cast<const unsigned*>(
                        lds_x + pix * 128 + ((cp2 * 4) ^ ((pix & 7) << 4)));
                    v[hy][cc] = par ? bfh(u) : bfl(u);
                }
            size_t ob = (size_t)n * OUTC * HW + (size_t)ty0 * WW + tx0 + lane;
#pragma unroll
            for (int r = 0; r < 4; ++r) {
                float tL = v[r][0],     tC = v[r][1],     tR = v[r][2];
                float mL = v[r + 1][0], mC = v[r + 1][1], mR = v[r + 1][2];
                float bL = v[r + 2][0], bC = v[r + 2][1], bR = v[r + 2][2];
                size_t rb = ob + (size_t)r * WW;
                out[rb + (size_t)(c * 3 + 0) * HW] = mC;
                out[rb + (size_t)(c * 3 + 1) * HW] = (tL + 2.f * tC + tR) - (bL + 2.f * bC + bR);
                out[rb + (size_t)(c * 3 + 2) * HW] = (tL - tR) + 2.f * (mL - mR) + (bL - bR);
                out[rb + (size_t)(192 + c)   * HW] = 4.f * mC - tC - bC - mL - mR;
            }
        }
    }

    // ---- epilogue: bias + 4x4 frag transpose via LDS, float4 stores.
    // lds rows: 32 f' x 272 floats (1088 B, +64B pad to spread banks)
    float* lds_f = reinterpret_cast<float*>(lds_x);
#pragma unroll
    for (int mt = 0; mt < 4; ++mt) {
        __syncthreads();
#pragma unroll
        for (int i = 0; i < 4; ++i) {
            int q = lk * 4 + i;
            int f = wf * 64 + mt * 16 + q;
            float bv = bl[f];
            int fp = wf * 16 + q;
#pragma unroll
            for (int j = 0; j < 4; ++j)
                lds_f[fp * 272 + wp * 64 + j * 16 + lr] = acc[mt][j][i] + bv;
        }
        __syncthreads();
#pragma unroll
        for (int p = 0; p < 4; ++p) {
            int e = tid + p * 512;        // 0..2047
            int fp = e >> 6;              // 0..31
            int xq = e & 63;
            float4 vv = *reinterpret_cast<const float4*>(lds_f + fp * 272 + xq * 4);
            int f = (fp >> 4) * 64 + mt * 16 + (fp & 15);
            int row = xq >> 4, xx = (xq & 15) * 4;
            *reinterpret_cast<float4*>(
                out + ((size_t)(n * OUTC + 256 + f)) * HW
                    + (size_t)(ty0 + row) * WW + tx0 + xx) = vv;
        }
    }
}

extern "C" void kernel_launch(void* const* d_in, const int* in_sizes, int n_in,
                              void* d_out, int out_size, void* d_ws, size_t ws_size,
                              hipStream_t stream) {
    const float* x  = (const float*)d_in[0];
    const float* Wl = (const float*)d_in[1];
    const float* bl = (const float*)d_in[2];
    float* out = (float*)d_out;

    wT_kernel<<<144, 256, 0, stream>>>(Wl, (unsigned*)d_ws);
    fused_kernel<<<NN * 256, 512, 0, stream>>>(x, (const unsigned short*)d_ws, bl, out);
}

// Round 5
// 322.788 us; speedup vs baseline: 1.0282x; 1.0222x over previous
//
#include <hip/hip_runtime.h>

#define HH 256
#define WW 256
#define CC 64
#define FF 128
#define NN 8
#define OUTC 384           // 3*C sep + C lap + F learned
#define HW (HH * WW)

typedef __attribute__((ext_vector_type(8))) short bf16x8;
typedef __attribute__((ext_vector_type(4))) float f32x4;

__device__ __forceinline__ int clampi(int v, int lo, int hi) {
    return v < lo ? lo : (v > hi ? hi : v);
}

// round-to-nearest-even fp32 -> bf16
static __device__ __forceinline__ unsigned short f2bf(float x) {
    unsigned u = __builtin_bit_cast(unsigned, x);
    u += 0x7FFFu + ((u >> 16) & 1u);
    return (unsigned short)(u >> 16);
}
static __device__ __forceinline__ unsigned packbf(float a, float b) {
    return (unsigned)f2bf(a) | ((unsigned)f2bf(b) << 16);
}
static __device__ __forceinline__ void nts(float* p, float a, float b, float c, float d) {
    f32x4 v = {a, b, c, d};
    __builtin_nontemporal_store(v, reinterpret_cast<f32x4*>(p));
}

// ---------------------------------------------------------------------------
// Kernel 0: W[f][c][3][3] fp32 -> ws bf16 [tap][f][c]   (9*128*64 elems)
// ---------------------------------------------------------------------------
__global__ __launch_bounds__(256) void wT_kernel(const float* __restrict__ Wl,
                                                 unsigned* __restrict__ wsW) {
    int e = blockIdx.x * 256 + threadIdx.x;     // over 9*128*32 = 36864 pairs
    if (e >= 9 * 128 * 32) return;
    int t = e >> 12;
    int rem = e & 4095;
    int f = rem >> 5;
    int c2 = rem & 31;
    float a = Wl[(size_t)f * 576 + (size_t)(2 * c2) * 9 + t];
    float b = Wl[(size_t)f * 576 + (size_t)(2 * c2 + 1) * 9 + t];
    wsW[t * 4096 + f * 32 + c2] = packbf(a, b);
}

// ---------------------------------------------------------------------------
// Block-specialized fused kernel, 18432 blocks x 512 thr, interleaved 1:8.
//  rm==0 -> learned block: 64x4 px tile, 128 f via bf16 MFMA (R4 path).
//  rm>0  -> dw block: (n,c,8 rows) fixed filters, pure streaming (R1 path).
// dw blocks keep the HBM pipe busy while learned blocks run MFMA.
// ---------------------------------------------------------------------------
__global__ __launch_bounds__(512, 2) void fused_kernel(const float* __restrict__ x,
                                                       const unsigned short* __restrict__ wsW,
                                                       const float* __restrict__ bl,
                                                       float* __restrict__ out) {
    __shared__ __align__(16) unsigned char lds_x[396 * 128];      // 50688 B

    int b = blockIdx.x;
    int q = b / 9;
    int rm = b - q * 9;

    if (rm != 0) {
        // ================= dw block: pure streaming depthwise =================
        int did = q * 8 + rm - 1;             // 0..16383
        int y8 = did & 31;
        int c = (did >> 5) & 63;
        int n = did >> 11;

        int t = threadIdx.x;
        int r = t >> 6;                       // 0..7
        int col = (t & 63) * 4;
        int y = y8 * 8 + r;

        const float* xp = x + ((size_t)(n * CC + c)) * HW;
        int ym = y == 0 ? 0 : y - 1;
        int yp = y == HH - 1 ? HH - 1 : y + 1;
        int cl = col == 0 ? 0 : col - 1;
        int cr = (col + 4 > WW - 1) ? WW - 1 : col + 4;

        float4 top = *(const float4*)(xp + (size_t)ym * WW + col);
        float4 mid = *(const float4*)(xp + (size_t)y  * WW + col);
        float4 bot = *(const float4*)(xp + (size_t)yp * WW + col);
        float tl = xp[(size_t)ym * WW + cl], tr = xp[(size_t)ym * WW + cr];
        float ml = xp[(size_t)y  * WW + cl], mr = xp[(size_t)y  * WW + cr];
        float blv = xp[(size_t)yp * WW + cl], br = xp[(size_t)yp * WW + cr];

        float tv[6] = {tl, top.x, top.y, top.z, top.w, tr};
        float mv[6] = {ml, mid.x, mid.y, mid.z, mid.w, mr};
        float bv[6] = {blv, bot.x, bot.y, bot.z, bot.w, br};

        float o0[4], o1[4], o2[4], o3[4];
#pragma unroll
        for (int j = 0; j < 4; ++j) {
            float tL = tv[j], tC = tv[j + 1], tR = tv[j + 2];
            float mL = mv[j], mC = mv[j + 1], mR = mv[j + 2];
            float bL = bv[j], bC = bv[j + 1], bR = bv[j + 2];
            o0[j] = mC;
            o1[j] = (tL + 2.0f * tC + tR) - (bL + 2.0f * bC + bR);
            o2[j] = (tL - tR) + 2.0f * (mL - mR) + (bL - bR);
            o3[j] = 4.0f * mC - tC - bC - mL - mR;
        }

        float* ob = out + ((size_t)n * OUTC) * HW + (size_t)y * WW + col;
        nts(ob + (size_t)(c * 3 + 0) * HW, o0[0], o0[1], o0[2], o0[3]);
        nts(ob + (size_t)(c * 3 + 1) * HW, o1[0], o1[1], o1[2], o1[3]);
        nts(ob + (size_t)(c * 3 + 2) * HW, o2[0], o2[1], o2[2], o2[3]);
        nts(ob + (size_t)(192 + c)   * HW, o3[0], o3[1], o3[2], o3[3]);
        return;
    }

    // ================= learned block: 64x4 px x 128 f MFMA =================
    int tile = q & 255;
    int n = q >> 8;
    int ty0 = (tile >> 2) * 4;            // 64 y-tiles of 4 rows
    int tx0 = (tile & 3) * 64;            // 4 x-tiles of 64 cols

    int tid = threadIdx.x;
    int lane = tid & 63;
    int w = tid >> 6;
    int wf = w >> 2;                      // f-half (0..1)
    int wp = w & 3;                       // tile row (0..3)
    int lr = lane & 15;
    int lk = lane >> 4;

    // ---- stage x tile: fp32 global -> bf16 LDS [pix][ch], swizzled. once.
    const float* xb = x + (size_t)n * CC * HW;
    for (int e = tid; e < 396 * 32; e += 512) {
        int cp = e / 396;
        int pix = e - cp * 396;
        int hy = pix / 66;
        int hx = pix - hy * 66;
        int gy = clampi(ty0 - 1 + hy, 0, HH - 1);
        int gx = clampi(tx0 - 1 + hx, 0, WW - 1);
        size_t gi = (size_t)(2 * cp) * HW + (size_t)gy * WW + gx;
        unsigned v = packbf(xb[gi], xb[gi + HW]);
        *reinterpret_cast<unsigned*>(lds_x + pix * 128 + ((cp * 4) ^ ((pix & 7) << 4))) = v;
    }
    __syncthreads();

    f32x4 acc[4][4] = {};                 // [mt (f tile)][j (16-px group)]

#pragma unroll
    for (int t = 0; t < 9; ++t) {
        int dy = t / 3, dx = t - 3 * (t / 3);

        // a-frags straight from L2-resident wsW[t][f][c]
        bf16x8 a[4][2];
#pragma unroll
        for (int mt = 0; mt < 4; ++mt)
#pragma unroll
            for (int kk = 0; kk < 2; ++kk) {
                int f = wf * 64 + mt * 16 + lr;
                a[mt][kk] = *reinterpret_cast<const bf16x8*>(
                    wsW + (size_t)t * 8192 + f * 64 + kk * 32 + lk * 8);
            }

#pragma unroll
        for (int kk = 0; kk < 2; ++kk) {
            int off = kk * 64 + lk * 16;
            bf16x8 bfr[4];
#pragma unroll
            for (int j = 0; j < 4; ++j) {
                int pix = (wp + dy) * 66 + j * 16 + lr + dx;
                bfr[j] = *reinterpret_cast<const bf16x8*>(
                    lds_x + pix * 128 + (off ^ ((pix & 7) << 4)));
            }
#pragma unroll
            for (int mt = 0; mt < 4; ++mt)
#pragma unroll
                for (int j = 0; j < 4; ++j)
                    acc[mt][j] = __builtin_amdgcn_mfma_f32_16x16x32_bf16(
                        a[mt][kk], bfr[j], acc[mt][j], 0, 0, 0);
        }
    }

    // ---- epilogue: bias + 4x4 frag transpose via LDS, float4 NT stores.
    float* lds_f = reinterpret_cast<float*>(lds_x);
#pragma unroll
    for (int mt = 0; mt < 4; ++mt) {
        __syncthreads();
#pragma unroll
        for (int i = 0; i < 4; ++i) {
            int qv = lk * 4 + i;
            int f = wf * 64 + mt * 16 + qv;
            float bv = bl[f];
            int fp = wf * 16 + qv;
#pragma unroll
            for (int j = 0; j < 4; ++j)
                lds_f[fp * 272 + wp * 64 + j * 16 + lr] = acc[mt][j][i] + bv;
        }
        __syncthreads();
#pragma unroll
        for (int p = 0; p < 4; ++p) {
            int e = tid + p * 512;        // 0..2047
            int fp = e >> 6;              // 0..31
            int xq = e & 63;
            const float* src = lds_f + fp * 272 + xq * 4;
            int f = (fp >> 4) * 64 + mt * 16 + (fp & 15);
            int row = xq >> 4, xx = (xq & 15) * 4;
            nts(out + ((size_t)(n * OUTC + 256 + f)) * HW
                    + (size_t)(ty0 + row) * WW + tx0 + xx,
                src[0], src[1], src[2], src[3]);
        }
    }
}

extern "C" void kernel_launch(void* const* d_in, const int* in_sizes, int n_in,
                              void* d_out, int out_size, void* d_ws, size_t ws_size,
                              hipStream_t stream) {
    const float* x  = (const float*)d_in[0];
    const float* Wl = (const float*)d_in[1];
    const float* bl = (const float*)d_in[2];
    float* out = (float*)d_out;

    wT_kernel<<<144, 256, 0, stream>>>(Wl, (unsigned*)d_ws);
    fused_kernel<<<2048 * 9, 512, 0, stream>>>(x, (const unsigned short*)d_ws, bl, out);
}